// Round 1
// baseline (9.567 us; speedup 1.0000x reference)
//
#include <hip/hip_runtime.h>
#include <float.h>

#define B 64
#define S 512
#define H 1024

// One block per (batch, entity). Threads 0..511 scan the S tokens for
// matches of ENT_BGN_IDS[e] = 997+e with attention_mask != 0, collect the
// matching positions in LDS, then cooperatively max-reduce the matched
// hidden rows over H and scatter the pooled vector to its two slots in the
// (B, 3, 2H) output.
__global__ __launch_bounds__(512) void entity_pool_kernel(
    const float* __restrict__ hidden,   // (B,S,H) f32
    const int*   __restrict__ ids,      // (B,S) i32
    const int*   __restrict__ amask,    // (B,S) i32
    float*       __restrict__ out)      // (B,3,2H) f32
{
    const int b = blockIdx.x;   // 0..B-1
    const int e = blockIdx.y;   // 0..2
    const int tid = threadIdx.x;

    __shared__ int match_pos[S];
    __shared__ int match_cnt;
    if (tid == 0) match_cnt = 0;
    __syncthreads();

    // one thread per token position
    {
        const int s = tid;
        const int id = ids[b * S + s];
        const int am = amask[b * S + s];
        if (id == (997 + e) && am != 0) {
            int slot = atomicAdd(&match_cnt, 1);
            match_pos[slot] = s;
        }
    }
    __syncthreads();

    const int cnt = match_cnt;

    // destination mapping for pooled[b, e, :]:
    //   e=0 (p0): out[b][0][0:H],  out[b][1][0:H]
    //   e=1 (p1): out[b][0][H:2H], out[b][2][0:H]
    //   e=2 (p2): out[b][1][H:2H], out[b][2][H:2H]
    int j0, half0, j1, half1;
    if (e == 0)      { j0 = 0; half0 = 0; j1 = 1; half1 = 0; }
    else if (e == 1) { j0 = 0; half0 = 1; j1 = 2; half1 = 0; }
    else             { j0 = 1; half0 = 1; j1 = 2; half1 = 1; }

    const long out_base = (long)b * 3 * (2 * H);
    float* dst0 = out + out_base + (long)j0 * (2 * H) + half0 * H;
    float* dst1 = out + out_base + (long)j1 * (2 * H) + half1 * H;

    const float* hb = hidden + (long)b * S * H;

    for (int h = tid; h < H; h += blockDim.x) {
        float v = 0.0f;
        if (cnt > 0) {
            v = -FLT_MAX;
            for (int i = 0; i < cnt; ++i) {
                v = fmaxf(v, hb[(long)match_pos[i] * H + h]);
            }
        }
        dst0[h] = v;
        dst1[h] = v;
    }
}

extern "C" void kernel_launch(void* const* d_in, const int* in_sizes, int n_in,
                              void* d_out, int out_size, void* d_ws, size_t ws_size,
                              hipStream_t stream) {
    const float* hidden = (const float*)d_in[0];
    const int*   ids    = (const int*)d_in[1];
    const int*   amask  = (const int*)d_in[2];
    float*       out    = (float*)d_out;

    dim3 grid(B, 3);
    entity_pool_kernel<<<grid, 512, 0, stream>>>(hidden, ids, amask, out);
}